// Round 1
// baseline (358.450 us; speedup 1.0000x reference)
//
#include <hip/hip_runtime.h>
#include <math.h>

// Problem constants (T,B,C,H,W) = (9,8,256,56,56), fp32 in/out.
#define TT 9
#define BN 8
#define CC 256
#define HW 3136            // 56*56
#define BHW (BN * HW)      // 25088
#define PIX 64             // pixels per block tile (3136 = 64*49 exactly)
#define CHUNKS (HW / PIX)  // 49
#define CENTER_T 4         // T/2

// Pass 1: score_other[t,b,hw] = sum_c seq[t,b,c,hw] * w_other[c]
// (score_center and bias b are constant over t -> softmax-invariant -> dropped)
// Block: 256 thr = 64 pixels (lanes, coalesced over hw) x 4 C-partitions.
__global__ __launch_bounds__(256) void scores_kernel(
    const float* __restrict__ seq, const float* __restrict__ w,
    float* __restrict__ scores) {
  int blk = blockIdx.x;
  int chunk = blk % CHUNKS;
  int tb = blk / CHUNKS;  // t*BN + b
  int tid = threadIdx.x;
  int pix = tid & 63;
  int cpart = tid >> 6;  // 0..3, each owns 64 channels

  __shared__ float w_other[CC];
  __shared__ float red[256];
  w_other[tid] = w[CC + tid];  // w[0, C:2C, 0, 0]
  __syncthreads();

  const float* base = seq + (size_t)tb * CC * HW + chunk * PIX + pix;
  int c0 = cpart * 64;
  float acc = 0.f;
#pragma unroll 8
  for (int cl = 0; cl < 64; ++cl) {
    int c = c0 + cl;
    acc = fmaf(base[(size_t)c * HW], w_other[c], acc);
  }
  red[tid] = acc;
  __syncthreads();
  if (cpart == 0) {
    float s = red[pix] + red[64 + pix] + red[128 + pix] + red[192 + pix];
    scores[(size_t)tb * HW + chunk * PIX + pix] = s;
  }
}

// Pass 2: in-place softmax over t for each of B*HW pixel columns.
__global__ __launch_bounds__(256) void softmax_kernel(float* __restrict__ scores) {
  int p = blockIdx.x * 256 + threadIdx.x;  // 0..BHW-1, grid sized exactly
  float v[TT];
  float m = -1e30f;
#pragma unroll
  for (int t = 0; t < TT; ++t) {
    v[t] = scores[(size_t)t * BHW + p];
    m = fmaxf(m, v[t]);
  }
  float s = 0.f;
#pragma unroll
  for (int t = 0; t < TT; ++t) {
    v[t] = __expf(v[t] - m);
    s += v[t];
  }
  float inv = 1.f / s;
#pragma unroll
  for (int t = 0; t < TT; ++t) scores[(size_t)t * BHW + p] = v[t] * inv;
}

// Pass 3: out[b,c,hw] = seq[4,b,c,hw] + gamma * sum_t attn[t,b,hw]*seq[t,b,c,hw]
// Block: 256 thr = 64 pixels x 4 csubs; each thread owns 4 channels so the
// 9 attn loads amortize over 4 outputs. Center captured in the t-loop.
__global__ __launch_bounds__(256) void attend_kernel(
    const float* __restrict__ seq, const float* __restrict__ attn,
    const float* __restrict__ gamma, float* __restrict__ out) {
  int blk = blockIdx.x;
  int chunk = blk % CHUNKS;
  int rest = blk / CHUNKS;
  int cg = rest % (CC / 16);
  int b = rest / (CC / 16);
  int tid = threadIdx.x;
  int pix = tid & 63;
  int csub = tid >> 6;
  int c0 = cg * 16 + csub * 4;
  int hwp = chunk * PIX + pix;

  float a[TT];
#pragma unroll
  for (int t = 0; t < TT; ++t) a[t] = attn[(size_t)t * BHW + b * HW + hwp];

  float acc[4] = {0.f, 0.f, 0.f, 0.f};
  float cen[4];
#pragma unroll
  for (int t = 0; t < TT; ++t) {
    float at = a[t];
#pragma unroll
    for (int i = 0; i < 4; ++i) {
      float v = seq[(((size_t)t * BN + b) * CC + (c0 + i)) * HW + hwp];
      acc[i] = fmaf(at, v, acc[i]);
      if (t == CENTER_T) cen[i] = v;
    }
  }
  float g = gamma[0];
#pragma unroll
  for (int i = 0; i < 4; ++i)
    out[((size_t)b * CC + (c0 + i)) * HW + hwp] = fmaf(g, acc[i], cen[i]);
}

extern "C" void kernel_launch(void* const* d_in, const int* in_sizes, int n_in,
                              void* d_out, int out_size, void* d_ws, size_t ws_size,
                              hipStream_t stream) {
  const float* seq = (const float*)d_in[0];
  const float* w = (const float*)d_in[1];
  // d_in[2] (bias b) is softmax-shift-invariant -> unused.
  const float* gamma = (const float*)d_in[3];
  float* out = (float*)d_out;
  float* scores = (float*)d_ws;  // needs T*B*HW*4 = 903168 B of ws

  scores_kernel<<<TT * BN * CHUNKS, 256, 0, stream>>>(seq, w, scores);
  softmax_kernel<<<BHW / 256, 256, 0, stream>>>(scores);
  attend_kernel<<<BN * (CC / 16) * CHUNKS, 256, 0, stream>>>(seq, scores, gamma, out);
}